// Round 8
// baseline (119.152 us; speedup 1.0000x reference)
//
#include <hip/hip_runtime.h>
#include <hip/hip_bf16.h>

static constexpr int Nc = 256;
static constexpr float NEGc = -1e30f;
static constexpr float SLOPEc = 0.01f;

using f32x4 = __attribute__((ext_vector_type(4))) float;
using s16x8 = __attribute__((ext_vector_type(8))) short;
typedef unsigned int u32;
typedef __attribute__((address_space(1))) const u32 gu32;
typedef __attribute__((address_space(3))) u32 lu32;

__device__ __forceinline__ void mfma16(f32x4& d, s16x8 a, s16x8 b) {
    // D = A(16x32)*B(32x16)+D ; A row=lane&15,k=(lane>>4)*8+reg ; B col=lane&15
    // C/D col=lane&15, row=(lane>>4)*4+reg   (validated rounds 1-7)
    asm("v_mfma_f32_16x16x32_bf16 %0, %1, %2, %0" : "+v"(d) : "v"(a), "v"(b));
}

// async global->LDS, 16B per lane; LDS dest = wave-uniform base + lane*16B
__device__ __forceinline__ void gload16(ushort* lds, const void* g) {
    __builtin_amdgcn_global_load_lds((gu32*)(unsigned long long)g,
                                     (lu32*)(unsigned long long)lds, 16, 0, 0);
}

__device__ __forceinline__ float wredMax(float v) {
#pragma unroll
    for (int o = 32; o; o >>= 1) v = fmaxf(v, __shfl_xor(v, o, 64));
    return v;
}
__device__ __forceinline__ float wredSum(float v) {
#pragma unroll
    for (int o = 32; o; o >>= 1) v += __shfl_xor(v, o, 64);
    return v;
}

__device__ __forceinline__ unsigned packhi(unsigned u1, unsigned u0) {
    return __builtin_amdgcn_perm(u1, u0, 0x07060302u);
}

// ---------------------------------------------------------------------------
// convert_all: fused split weights F = [ W | W@Wa | W@Wb ] ([chunk][448][8]
// hi/lo) and fused 448-wide biases [ b | b@Wa | b@Wb+ab1 ].
// items: [0,43520) W-split, [43520,182784) WA, [182784,183680) bias
// ---------------------------------------------------------------------------
__global__ void __launch_bounds__(256) convert_all(
    const float* __restrict__ W0, const float* __restrict__ b0,
    const float* __restrict__ W1, const float* __restrict__ b1,
    const float* __restrict__ A1, const float* __restrict__ ab1,
    ushort* __restrict__ F0h, ushort* __restrict__ F0l,
    ushort* __restrict__ F1h, ushort* __restrict__ F1l,
    float* __restrict__ bias0, float* __restrict__ bias1) {
    int idx = blockIdx.x * 256 + threadIdx.x;
    if (idx >= 183680) return;

    if (idx < 43520) {
        const float* src; ushort *dh, *dl; int K, ch, c;
        if (idx < 30720) { src = W0; dh = F0h; dl = F0l; K = 768;
                           ch = idx / 320; c = idx - ch * 320; }
        else { int off = idx - 30720; src = W1; dh = F1h; dl = F1l; K = 300;
               ch = off / 320; c = off - ch * 320; }
        float v[8];
#pragma unroll
        for (int e = 0; e < 8; e++) {
            int k = ch * 8 + e;
            v[e] = (k < K && c < 300) ? src[(size_t)k * 300 + c] : 0.f;
        }
        unsigned hu[4], lu[4];
#pragma unroll
        for (int q = 0; q < 4; q++) {
            unsigned u0 = __float_as_uint(v[q * 2]);
            unsigned u1 = __float_as_uint(v[q * 2 + 1]);
            float r0 = v[q * 2] - __uint_as_float(u0 & 0xFFFF0000u);
            float r1 = v[q * 2 + 1] - __uint_as_float(u1 & 0xFFFF0000u);
            hu[q] = packhi(u1, u0);
            lu[q] = packhi(__float_as_uint(r1), __float_as_uint(r0));
        }
        size_t dst = ((size_t)ch * 448 + c) * 8;
        *(uint4*)&dh[dst] = make_uint4(hu[0], hu[1], hu[2], hu[3]);
        *(uint4*)&dl[dst] = make_uint4(lu[0], lu[1], lu[2], lu[3]);
    } else if (idx < 182784) {
        // WA: one 300-MAC dot per thread
        const float* Wsrc; ushort *dh, *dl; int K, idx2;
        if (idx < 141824) { idx2 = idx - 43520; Wsrc = W0; dh = F0h; dl = F0l; K = 768; }
        else { idx2 = idx - 141824; Wsrc = W1; dh = F1h; dl = F1l; K = 300; }
        int k = idx2 >> 7, c = idx2 & 127;
        float accv = 0.f;
        if (k < K) {
            const float* wrow = Wsrc + (size_t)k * 300;
            const float* a1c = (c < 64) ? (A1 + c) : (A1 + 300 * 64 + (c - 64));
            for (int mm = 0; mm < 300; mm += 4) {
                accv += wrow[mm] * a1c[(size_t)mm * 64]
                      + wrow[mm + 1] * a1c[(size_t)(mm + 1) * 64]
                      + wrow[mm + 2] * a1c[(size_t)(mm + 2) * 64]
                      + wrow[mm + 3] * a1c[(size_t)(mm + 3) * 64];
            }
        }
        unsigned u = __float_as_uint(accv);
        float r = accv - __uint_as_float(u & 0xFFFF0000u);
        size_t dst = ((size_t)(k >> 3) * 448 + 320 + c) * 8 + (k & 7);
        dh[dst] = (ushort)(u >> 16);
        dl[dst] = (ushort)(__float_as_uint(r) >> 16);
    } else {
        int off = idx - 182784;
        int layer = off / 448, col = off - layer * 448;
        const float* b = layer ? b1 : b0;
        float v;
        if (col < 320) {
            v = (col < 300) ? b[col] : 0.f;
        } else {
            int cc = col - 320;
            const float* a1c = (cc < 64) ? (A1 + cc) : (A1 + 300 * 64 + (cc - 64));
            float s = 0.f;
            for (int mm = 0; mm < 300; mm++) s += b[mm] * a1c[(size_t)mm * 64];
            v = s + ((cc >= 64) ? ab1[cc - 64] : 0.f);
        }
        (layer ? bias1 : bias0)[col] = v;
    }
}

// ---------------------------------------------------------------------------
// Hybrid async GEMM core: 64x64 tile, split-bf16 3-pass MFMA, double-buffered,
// ONE barrier per K-step. B always via global_load_lds (pre-split slabs).
// A: APRE ? global_load_lds from slabs : fp32 reg-load + in-register split.
// smem (ushort): buf*8192 + {Ah:0, Al:2048, Bh:4096, Bl:6144}
// ---------------------------------------------------------------------------
template<bool APRE>
__device__ __forceinline__ void gemm_core_h(
    ushort* smem,
    const float* __restrict__ Afp, int AS,
    const char* __restrict__ AhB, const char* __restrict__ AlB,
    const char* __restrict__ BhB, const char* __restrict__ BlB,
    int WCOLS, int col0, int Kp, f32x4 (&acc)[2][2]) {
    const int tid = threadIdx.x;
    const int lane = tid & 63, wave = tid >> 6;
    const int wm = wave >> 1, wn = wave & 1;
    const int m = lane & 15, kch = lane >> 4;
    const int arow = tid >> 2, aoff = (tid & 3) * 8;

    float fa[8];
    auto loadrgA = [&](int kk) {
        const float* p = Afp + (size_t)arow * AS + aoff + kk;
        *(float4*)&fa[0] = *(const float4*)(p);
        *(float4*)&fa[4] = *(const float4*)(p + 4);
    };
    auto stageA = [&](int buf) {
#pragma unroll
        for (int q = 0; q < 2; q++) {
            unsigned u0 = __float_as_uint(fa[q * 4 + 0]);
            unsigned u1 = __float_as_uint(fa[q * 4 + 1]);
            unsigned u2 = __float_as_uint(fa[q * 4 + 2]);
            unsigned u3 = __float_as_uint(fa[q * 4 + 3]);
            float r0 = fa[q * 4 + 0] - __uint_as_float(u0 & 0xFFFF0000u);
            float r1 = fa[q * 4 + 1] - __uint_as_float(u1 & 0xFFFF0000u);
            float r2 = fa[q * 4 + 2] - __uint_as_float(u2 & 0xFFFF0000u);
            float r3 = fa[q * 4 + 3] - __uint_as_float(u3 & 0xFFFF0000u);
            uint2 th, tl;
            th.x = packhi(u1, u0); th.y = packhi(u3, u2);
            tl.x = packhi(__float_as_uint(r1), __float_as_uint(r0));
            tl.y = packhi(__float_as_uint(r3), __float_as_uint(r2));
            int kq = aoff + q * 4;
            int base = buf * 8192 + ((kq >> 3) * 64 + arow) * 8 + (kq & 7);
            *(uint2*)&smem[base] = th;
            *(uint2*)&smem[base + 2048] = tl;
        }
    };
    auto issueA = [&](int k0, int buf) {
        size_t ao = (size_t)k0 * 128 + wave * 1024 + lane * 16;
        gload16(smem + buf * 8192 + wave * 512, AhB + ao);
        gload16(smem + buf * 8192 + 2048 + wave * 512, AlB + ao);
    };
    auto issueB = [&](int k0, int buf) {
        size_t bo = ((size_t)((k0 >> 3) + wave) * WCOLS + col0 + lane) * 16;
        gload16(smem + buf * 8192 + 4096 + wave * 512, BhB + bo);
        gload16(smem + buf * 8192 + 6144 + wave * 512, BlB + bo);
    };

    if constexpr (APRE) issueA(0, 0); else loadrgA(0);
    issueB(0, 0);
    if constexpr (!APRE) { stageA(0); if (Kp > 32) loadrgA(32); }
    __syncthreads();   // vmcnt+lgkm drained at barrier

    for (int k0 = 0; k0 < Kp; k0 += 32) {
        const int cur = (k0 >> 5) & 1;
        if (k0 + 32 < Kp) {   // next-tile staging overlaps ds_read+MFMA below
            if constexpr (APRE) issueA(k0 + 32, cur ^ 1);
            issueB(k0 + 32, cur ^ 1);
            if constexpr (!APRE) { stageA(cur ^ 1); if (k0 + 64 < Kp) loadrgA(k0 + 64); }
        }
        s16x8 Afh[2], Afl[2], Bfh[2], Bfl[2];
#pragma unroll
        for (int fr = 0; fr < 2; fr++) {
            int off = cur * 8192 + (kch * 64 + wm * 32 + fr * 16 + m) * 8;
            Afh[fr] = *(const s16x8*)&smem[off];
            Afl[fr] = *(const s16x8*)&smem[off + 2048];
        }
#pragma unroll
        for (int fc = 0; fc < 2; fc++) {
            int off = cur * 8192 + 4096 + (kch * 64 + wn * 32 + fc * 16 + m) * 8;
            Bfh[fc] = *(const s16x8*)&smem[off];
            Bfl[fc] = *(const s16x8*)&smem[off + 2048];
        }
#pragma unroll
        for (int fr = 0; fr < 2; fr++)
#pragma unroll
            for (int fc = 0; fc < 2; fc++) {
                mfma16(acc[fr][fc], Afh[fr], Bfh[fc]);
                mfma16(acc[fr][fc], Afl[fr], Bfh[fc]);
                mfma16(acc[fr][fc], Afh[fr], Bfl[fc]);
            }
        __syncthreads();
    }
}

// ---------------------------------------------------------------------------
// xf: [ h-split | si | sjT ] = X @ F + bias   (448 cols)
// APRE=false: X fp32 (feature); APRE=true: X pre-split slabs (x1 from pv L0)
// ---------------------------------------------------------------------------
template<bool APRE>
__global__ void __launch_bounds__(256) xf_kernel(
    const float* __restrict__ Xf,
    const ushort* __restrict__ XAh, const ushort* __restrict__ XAl,
    int Kp,
    const ushort* __restrict__ Fh, const ushort* __restrict__ Fl,
    const float* __restrict__ bias,
    ushort* __restrict__ Hh, ushort* __restrict__ Hl,
    float* __restrict__ si, float* __restrict__ sjT) {
    __shared__ __align__(16) ushort smem[16384];
    const int tid = threadIdx.x;
    const int lane = tid & 63, wave = tid >> 6;
    const int wm = wave >> 1, wn = wave & 1;
    const int m = lane & 15, kch = lane >> 4;
    const int row0 = blockIdx.y * 64, col0 = blockIdx.x * 64;

    f32x4 acc[2][2];
#pragma unroll
    for (int i = 0; i < 2; i++)
#pragma unroll
        for (int j = 0; j < 2; j++)
#pragma unroll
            for (int e = 0; e < 4; e++) acc[i][j][e] = 0.f;

    const float* Afp = APRE ? nullptr : (Xf + (size_t)row0 * Kp);
    const char* AhB = APRE ? (const char*)(XAh + (size_t)blockIdx.y * Kp * 64) : nullptr;
    const char* AlB = APRE ? (const char*)(XAl + (size_t)blockIdx.y * Kp * 64) : nullptr;
    gemm_core_h<APRE>(smem, Afp, Kp, AhB, AlB,
                      (const char*)Fh, (const char*)Fl, 448, col0, Kp, acc);
    asm volatile("s_nop 7\ns_nop 7\ns_nop 7" ::);   // MFMA->VALU hazard guard

#pragma unroll
    for (int fr = 0; fr < 2; fr++) {
        int rbase = row0 + wm * 32 + fr * 16 + (kch << 2);
#pragma unroll
        for (int fc = 0; fc < 2; fc++) {
            int col = col0 + wn * 32 + fc * 16 + m;
            float bv = bias[col];
            float vv[4];
#pragma unroll
            for (int e = 0; e < 4; e++) vv[e] = acc[fr][fc][e] + bv;
            if (col < 320) {           // h -> hi/lo split, H slab layout
                unsigned u0 = __float_as_uint(vv[0]);
                unsigned u1 = __float_as_uint(vv[1]);
                unsigned u2 = __float_as_uint(vv[2]);
                unsigned u3 = __float_as_uint(vv[3]);
                float r0 = vv[0] - __uint_as_float(u0 & 0xFFFF0000u);
                float r1 = vv[1] - __uint_as_float(u1 & 0xFFFF0000u);
                float r2 = vv[2] - __uint_as_float(u2 & 0xFFFF0000u);
                float r3 = vv[3] - __uint_as_float(u3 & 0xFFFF0000u);
                uint2 th, tl;
                th.x = packhi(u1, u0); th.y = packhi(u3, u2);
                tl.x = packhi(__float_as_uint(r1), __float_as_uint(r0));
                tl.y = packhi(__float_as_uint(r3), __float_as_uint(r2));
                int k = rbase & 255, bb = rbase >> 8;
                size_t dst = (size_t)bb * 81920 + ((size_t)(k >> 3) * 320 + col) * 8 + (k & 7);
                *(uint2*)&Hh[dst] = th;
                *(uint2*)&Hl[dst] = tl;
            } else if (col < 384) {    // si fp32
                int cc = col - 320;
#pragma unroll
                for (int e = 0; e < 4; e++)
                    si[(size_t)(rbase + e) * 64 + cc] = vv[e];
            } else {                   // sjT fp32 (transposed, coalesced)
                int cc = col - 384;
                int bb = rbase >> 8, j0 = rbase & 255;
                float4 v4 = make_float4(vv[0], vv[1], vv[2], vv[3]);
                *(float4*)&sjT[((size_t)(bb * 64 + cc)) * Nc + j0] = v4;
            }
        }
    }
}

// ---------------------------------------------------------------------------
// scores: 16 rows per block, grid (16 batches, 16 tiles) = 256 blocks (1/CU).
// e = leaky(a2 . relu(si+sj)), mask, per-row max/sum-exp,
// P = exp(e-rowmax) written SPLIT bf16 in PV slab layout [slab][kc][64][8].
// ---------------------------------------------------------------------------
__global__ void __launch_bounds__(256) scores_kernel(
    const float* __restrict__ si, const float* __restrict__ sjT,
    const float* __restrict__ adj, const float* __restrict__ A2,
    const float* __restrict__ ab2p,
    ushort* __restrict__ Ph, ushort* __restrict__ Pl,
    float* __restrict__ rmx, float* __restrict__ rsm) {
    int b = blockIdx.x, ic = blockIdx.y;
    const int j = threadIdx.x;
    __shared__ __align__(16) float sis[16][68];
    __shared__ __align__(16) float a2s[64];
    __shared__ __align__(16) float E[16][260];

    if (j < 64) a2s[j] = A2[j];
#pragma unroll
    for (int t = 0; t < 4; t++) {
        int idx = j + t * 256;
        int r = idx >> 6, h = idx & 63;
        sis[r][h] = si[(size_t)(b * Nc + ic * 16 + r) * 64 + h];
    }
    float sv[64];
    const float* sjb = sjT + ((size_t)b << 6) * Nc + j;
#pragma unroll
    for (int h = 0; h < 64; h++) sv[h] = sjb[(size_t)h * Nc];
    __syncthreads();

    float acc[16] = {};
#pragma unroll 4
    for (int hq = 0; hq < 16; hq++) {
        float4 a2q = *(const float4*)&a2s[hq * 4];
        float s0 = sv[hq * 4 + 0], s1 = sv[hq * 4 + 1];
        float s2 = sv[hq * 4 + 2], s3 = sv[hq * 4 + 3];
#pragma unroll
        for (int r = 0; r < 16; r++) {
            const float4 siq = *(const float4*)&sis[r][hq * 4];
            acc[r] += a2q.x * fmaxf(siq.x + s0, 0.f)
                    + a2q.y * fmaxf(siq.y + s1, 0.f)
                    + a2q.z * fmaxf(siq.z + s2, 0.f)
                    + a2q.w * fmaxf(siq.w + s3, 0.f);
        }
    }
    float ab2v = ab2p[0];
    const float* adjp = adj + (size_t)(b * Nc + ic * 16) * Nc + j;
#pragma unroll
    for (int r = 0; r < 16; r++) {
        float e = acc[r] + ab2v;
        e = e > 0.f ? e : SLOPEc * e;
        float a = adjp[(size_t)r * Nc];
        E[r][j] = (a != 0.f) ? e : NEGc;
    }
    __syncthreads();
    int wv = j >> 6, lane = j & 63;
#pragma unroll
    for (int rr = 0; rr < 4; rr++) {
        int r = wv * 4 + rr;
        float4 q = *(const float4*)&E[r][lane * 4];
        float m4 = fmaxf(fmaxf(q.x, q.y), fmaxf(q.z, q.w));
        float rm = wredMax(m4);
        float4 p;
        p.x = expf(q.x - rm); p.y = expf(q.y - rm);
        p.z = expf(q.z - rm); p.w = expf(q.w - rm);
        float rs = wredSum(p.x + p.y + p.z + p.w);
        int gi = ic * 16 + r;
        // split write, PV slab layout
        unsigned u0 = __float_as_uint(p.x), u1 = __float_as_uint(p.y);
        unsigned u2 = __float_as_uint(p.z), u3 = __float_as_uint(p.w);
        float r0 = p.x - __uint_as_float(u0 & 0xFFFF0000u);
        float r1 = p.y - __uint_as_float(u1 & 0xFFFF0000u);
        float r2 = p.z - __uint_as_float(u2 & 0xFFFF0000u);
        float r3 = p.w - __uint_as_float(u3 & 0xFFFF0000u);
        int slab = (b << 2) + (gi >> 6);
        size_t base = (size_t)slab * 16384 + (size_t)(lane >> 1) * 512
                    + (gi & 63) * 8 + ((lane & 1) << 2);
        *(uint2*)&Ph[base] = make_uint2(packhi(u1, u0), packhi(u3, u2));
        *(uint2*)&Pl[base] = make_uint2(packhi(__float_as_uint(r1), __float_as_uint(r0)),
                                        packhi(__float_as_uint(r3), __float_as_uint(r2)));
        if (lane == 0) { rmx[b * Nc + gi] = rm; rsm[b * Nc + gi] = rs; }
    }
}

// ---------------------------------------------------------------------------
// pv: out_rows = softmax_scale * (P @ H); both operands via global_load_lds.
// SPLIT: epilogue writes x1 split slabs via LDS transpose; else fp32 out.
// ---------------------------------------------------------------------------
template<bool SPLIT>
__global__ void __launch_bounds__(256) pv_kernel(
    const ushort* __restrict__ Ph, const ushort* __restrict__ Pl,
    const ushort* __restrict__ Hh, const ushort* __restrict__ Hl,
    const float* __restrict__ rmx, const float* __restrict__ rsm,
    ushort* __restrict__ X1h, ushort* __restrict__ X1l,
    float* __restrict__ out, int OS) {
    __shared__ __align__(16) ushort smem[16384];
    __shared__ float sclS[256];
    __shared__ float mb[4], sb[4];
    const int tid = threadIdx.x;
    const int lane = tid & 63, wave = tid >> 6;
    const int wm = wave >> 1, wn = wave & 1;
    const int m = lane & 15, kch = lane >> 4;
    const int col0 = blockIdx.x * 64, row0 = blockIdx.y * 64;
    const int b = blockIdx.z;

    {   // flat-softmax merge: scale_i = exp(m_i - M)/S
        float mv = rmx[b * 256 + tid];
        float wmx = wredMax(mv);
        if (!lane) mb[wave] = wmx;
        __syncthreads();
        float M = fmaxf(fmaxf(mb[0], mb[1]), fmaxf(mb[2], mb[3]));
        float ex = expf(mv - M);
        float ws = wredSum(rsm[b * 256 + tid] * ex);
        if (!lane) sb[wave] = ws;
        __syncthreads();
        float S = sb[0] + sb[1] + sb[2] + sb[3];
        sclS[tid] = ex / S;
        __syncthreads();
    }

    f32x4 acc[2][2];
#pragma unroll
    for (int i = 0; i < 2; i++)
#pragma unroll
        for (int j = 0; j < 2; j++)
#pragma unroll
            for (int e = 0; e < 4; e++) acc[i][j][e] = 0.f;

    const int slab = (b << 2) + blockIdx.y;
    gemm_core_h<true>(smem, nullptr, 0,
                      (const char*)(Ph + (size_t)slab * 16384),
                      (const char*)(Pl + (size_t)slab * 16384),
                      (const char*)(Hh + (size_t)b * 81920),
                      (const char*)(Hl + (size_t)b * 81920),
                      320, col0, 256, acc);
    asm volatile("s_nop 7\ns_nop 7\ns_nop 7" ::);

    if constexpr (SPLIT) {
        // stash scaled acc into LDS [64 cols][66], then coalesced split write
        float* LF = (float*)smem;
#pragma unroll
        for (int fr = 0; fr < 2; fr++) {
            int rrel = wm * 32 + fr * 16 + (kch << 2);
#pragma unroll
            for (int fc = 0; fc < 2; fc++) {
                int crel = wn * 32 + fc * 16 + m;
#pragma unroll
                for (int e = 0; e < 4; e++)
                    LF[crel * 66 + rrel + e] = acc[fr][fc][e] * sclS[row0 + rrel + e];
            }
        }
        __syncthreads();
        for (int it = tid; it < 512; it += 256) {
            int cr = it >> 6, row = it & 63;
            float v[8];
#pragma unroll
            for (int e = 0; e < 8; e++) v[e] = LF[(cr * 8 + e) * 66 + row];
            unsigned hu[4], lu[4];
#pragma unroll
            for (int q = 0; q < 4; q++) {
                unsigned u0 = __float_as_uint(v[q * 2]);
                unsigned u1 = __float_as_uint(v[q * 2 + 1]);
                float r0 = v[q * 2] - __uint_as_float(u0 & 0xFFFF0000u);
                float r1 = v[q * 2 + 1] - __uint_as_float(u1 & 0xFFFF0000u);
                hu[q] = packhi(u1, u0);
                lu[q] = packhi(__float_as_uint(r1), __float_as_uint(r0));
            }
            size_t dst = (size_t)slab * 20480 + ((size_t)(col0 >> 3) + cr) * 512 + row * 8;
            *(uint4*)&X1h[dst] = make_uint4(hu[0], hu[1], hu[2], hu[3]);
            *(uint4*)&X1l[dst] = make_uint4(lu[0], lu[1], lu[2], lu[3]);
        }
    } else {
        float* ob = out + (size_t)b * 256 * OS;
#pragma unroll
        for (int fr = 0; fr < 2; fr++) {
            int rbase = row0 + wm * 32 + fr * 16 + (kch << 2);
#pragma unroll
            for (int fc = 0; fc < 2; fc++) {
                int col = col0 + wn * 32 + fc * 16 + m;
                if (col < OS) {
#pragma unroll
                    for (int e = 0; e < 4; e++)
                        ob[(size_t)(rbase + e) * OS + col] = acc[fr][fc][e] * sclS[rbase + e];
                }
            }
        }
    }
}

// ---------------------------------------------------------------------------
extern "C" void kernel_launch(void* const* d_in, const int* in_sizes, int n_in,
                              void* d_out, int out_size, void* d_ws, size_t ws_size,
                              hipStream_t stream) {
    const float* adj     = (const float*)d_in[0];
    const float* feature = (const float*)d_in[1];
    const float* W0      = (const float*)d_in[2];
    const float* b0      = (const float*)d_in[3];
    const float* W1      = (const float*)d_in[4];
    const float* b1      = (const float*)d_in[5];
    const float* A1      = (const float*)d_in[6];
    const float* ab1     = (const float*)d_in[7];
    const float* A2      = (const float*)d_in[8];
    const float* ab2     = (const float*)d_in[9];

    char* ws = (char*)d_ws;
    ushort* X1h   = (ushort*)(ws);                 // 16 slabs x 20480  2,621,440
    ushort* X1l   = (ushort*)(ws + 2621440);       //                   2,621,440
    float*  si    = (float*)(ws + 5242880);        //                   1,048,576
    float*  sjT   = (float*)(ws + 6291456);        //                   1,048,576
    ushort* Ph    = (ushort*)(ws + 7340032);       // 64 slabs x 16384  2,097,152
    ushort* Pl    = (ushort*)(ws + 9437184);       //                   2,097,152
    float*  rmx   = (float*)(ws + 11534336);       //                   16,384
    float*  rsm   = (float*)(ws + 11550720);       //                   16,384
    float*  bias0 = (float*)(ws + 11567104);       //                   1,792
    float*  bias1 = (float*)(ws + 11568896);       //                   1,792
    ushort* F0h   = (ushort*)(ws + 11570688);      //                   688,128
    ushort* F0l   = (ushort*)(ws + 12258816);      //                   688,128
    ushort* F1h   = (ushort*)(ws + 12946944);      //                   286,720
    ushort* F1l   = (ushort*)(ws + 13233664);      //                   286,720
    ushort* Hh    = (ushort*)(ws + 13520384);      // 16 x 81920        2,621,440
    ushort* Hl    = (ushort*)(ws + 16141824);      //                   2,621,440
    float* outp   = (float*)d_out;

    convert_all<<<718, 256, 0, stream>>>(W0, b0, W1, b1, A1, ab1,
                                         F0h, F0l, F1h, F1l, bias0, bias1);

    // layer 0: A = feature fp32 (reg-staged)
    xf_kernel<false><<<dim3(7, 64), 256, 0, stream>>>(
        feature, nullptr, nullptr, 768, F0h, F0l, bias0, Hh, Hl, si, sjT);
    scores_kernel<<<dim3(16, 16), 256, 0, stream>>>(
        si, sjT, adj, A2, ab2, Ph, Pl, rmx, rsm);
    pv_kernel<true><<<dim3(5, 4, 16), 256, 0, stream>>>(
        Ph, Pl, Hh, Hl, rmx, rsm, X1h, X1l, nullptr, 0);

    // layer 1: A = x1 pre-split slabs (global_load_lds)
    xf_kernel<true><<<dim3(7, 64), 256, 0, stream>>>(
        nullptr, X1h, X1l, 320, F1h, F1l, bias1, Hh, Hl, si, sjT);
    scores_kernel<<<dim3(16, 16), 256, 0, stream>>>(
        si, sjT, adj, A2, ab2, Ph, Pl, rmx, rsm);
    pv_kernel<false><<<dim3(5, 4, 16), 256, 0, stream>>>(
        Ph, Pl, Hh, Hl, rmx, rsm, nullptr, nullptr, outp, 300);
}

// Round 9
// 94.611 us; speedup vs baseline: 1.2594x; 1.2594x over previous
//
#include <hip/hip_runtime.h>
#include <hip/hip_bf16.h>

static constexpr int Nc = 256;
static constexpr float NEGc = -1e30f;
static constexpr float SLOPEc = 0.01f;

using f32x4 = __attribute__((ext_vector_type(4))) float;
using s16x8 = __attribute__((ext_vector_type(8))) short;

__device__ __forceinline__ void mfma16(f32x4& d, s16x8 a, s16x8 b) {
    // D = A(16x32)*B(32x16)+D ; A row=lane&15,k=(lane>>4)*8+reg ; B col=lane&15
    // C/D col=lane&15, row=(lane>>4)*4+reg   (validated rounds 1-8)
    asm("v_mfma_f32_16x16x32_bf16 %0, %1, %2, %0" : "+v"(d) : "v"(a), "v"(b));
}

// LDS-only barrier: drains ds ops but leaves global register loads in flight
// (avoids the compiler's vmcnt(0) drain before s_barrier — T4 pattern).
__device__ __forceinline__ void barrier_lds() {
    asm volatile("s_waitcnt lgkmcnt(0)\n\ts_barrier" ::: "memory");
}

__device__ __forceinline__ float wredMax(float v) {
#pragma unroll
    for (int o = 32; o; o >>= 1) v = fmaxf(v, __shfl_xor(v, o, 64));
    return v;
}
__device__ __forceinline__ float wredSum(float v) {
#pragma unroll
    for (int o = 32; o; o >>= 1) v += __shfl_xor(v, o, 64);
    return v;
}

__device__ __forceinline__ unsigned packhi(unsigned u1, unsigned u0) {
    return __builtin_amdgcn_perm(u1, u0, 0x07060302u);
}

// ---------------------------------------------------------------------------
// Conversion work items (shared by convert0 kernel and xf-L0 fused blocks).
// F layout: [k>>3][448][8] hi/lo ; bias: [ b | b@Wa | b@Wb+ab1 ] (448)
// ---------------------------------------------------------------------------
__device__ __forceinline__ void do_wsplit(
    const float* __restrict__ src, int K, int ch, int c,
    ushort* __restrict__ dh, ushort* __restrict__ dl) {
    float v[8];
#pragma unroll
    for (int e = 0; e < 8; e++) {
        int k = ch * 8 + e;
        v[e] = (k < K && c < 300) ? src[(size_t)k * 300 + c] : 0.f;
    }
    unsigned hu[4], lu[4];
#pragma unroll
    for (int q = 0; q < 4; q++) {
        unsigned u0 = __float_as_uint(v[q * 2]);
        unsigned u1 = __float_as_uint(v[q * 2 + 1]);
        float r0 = v[q * 2] - __uint_as_float(u0 & 0xFFFF0000u);
        float r1 = v[q * 2 + 1] - __uint_as_float(u1 & 0xFFFF0000u);
        hu[q] = packhi(u1, u0);
        lu[q] = packhi(__float_as_uint(r1), __float_as_uint(r0));
    }
    size_t dst = ((size_t)ch * 448 + c) * 8;
    *(uint4*)&dh[dst] = make_uint4(hu[0], hu[1], hu[2], hu[3]);
    *(uint4*)&dl[dst] = make_uint4(lu[0], lu[1], lu[2], lu[3]);
}

__device__ __forceinline__ void do_wa(
    const float* __restrict__ Wsrc, int K, int k, int c,
    const float* __restrict__ A1,
    ushort* __restrict__ dh, ushort* __restrict__ dl) {
    float accv = 0.f;
    if (k < K) {
        const float* wrow = Wsrc + (size_t)k * 300;
        const float* a1c = (c < 64) ? (A1 + c) : (A1 + 300 * 64 + (c - 64));
        for (int mm = 0; mm < 300; mm += 4) {
            accv += wrow[mm] * a1c[(size_t)mm * 64]
                  + wrow[mm + 1] * a1c[(size_t)(mm + 1) * 64]
                  + wrow[mm + 2] * a1c[(size_t)(mm + 2) * 64]
                  + wrow[mm + 3] * a1c[(size_t)(mm + 3) * 64];
        }
    }
    unsigned u = __float_as_uint(accv);
    float r = accv - __uint_as_float(u & 0xFFFF0000u);
    size_t dst = ((size_t)(k >> 3) * 448 + 320 + c) * 8 + (k & 7);
    dh[dst] = (ushort)(u >> 16);
    dl[dst] = (ushort)(__float_as_uint(r) >> 16);
}

__device__ __forceinline__ void do_bias(
    const float* __restrict__ b, int col,
    const float* __restrict__ A1, const float* __restrict__ ab1,
    float* __restrict__ biasOut) {
    float v;
    if (col < 320) {
        v = (col < 300) ? b[col] : 0.f;
    } else {
        int cc = col - 320;
        const float* a1c = (cc < 64) ? (A1 + cc) : (A1 + 300 * 64 + (cc - 64));
        float s = 0.f;
        for (int mm = 0; mm < 300; mm++) s += b[mm] * a1c[(size_t)mm * 64];
        v = s + ((cc >= 64) ? ab1[cc - 64] : 0.f);
    }
    biasOut[col] = v;
}

// convert0: layer-0 weights only.  items: [0,30720) W0-split,
// [30720,129024) WA0, [129024,129472) bias0
__global__ void __launch_bounds__(256) convert0(
    const float* __restrict__ W0, const float* __restrict__ b0,
    const float* __restrict__ A1, const float* __restrict__ ab1,
    ushort* __restrict__ F0h, ushort* __restrict__ F0l,
    float* __restrict__ bias0) {
    int idx = blockIdx.x * 256 + threadIdx.x;
    if (idx >= 129472) return;
    if (idx < 30720) {
        do_wsplit(W0, 768, idx / 320, idx % 320, F0h, F0l);
    } else if (idx < 129024) {
        int i2 = idx - 30720;
        do_wa(W0, 768, i2 >> 7, i2 & 127, A1, F0h, F0l);
    } else {
        do_bias(b0, idx - 129024, A1, ab1, bias0);
    }
}

// ---------------------------------------------------------------------------
// GEMM core: 64x64 tile, split-bf16 3-pass MFMA, double-buffered LDS,
// ONE LDS-only barrier per K-step; register prefetch loads stay in flight
// across barriers (no vmcnt drain).
// ---------------------------------------------------------------------------
__device__ __forceinline__ void gemm_core(
    const float* __restrict__ Ab, const ushort* __restrict__ Whb,
    const ushort* __restrict__ Wlb, int WCOLS, int col0, int Kp,
    f32x4 (&acc)[2][2]) {
    __shared__ __align__(16) short Ah[2][2048], Al[2][2048];
    __shared__ __align__(16) short Bh[2][2048], Bl[2][2048];
    const int tid = threadIdx.x;
    const int lane = tid & 63, wave = tid >> 6;
    const int wm = wave >> 1, wn = wave & 1;
    const int m = lane & 15, kch = lane >> 4;
    const int arow = tid >> 2, aoff = (tid & 3) * 8;
    const int bchunk = tid >> 6, bcol = tid & 63;
    const int bsel = (bchunk * 64 + bcol) * 8;

    float fa[8];
    s16x8 bhv, blv;

    auto loadrg = [&](int kk) {
        *(float4*)&fa[0] = *(const float4*)(Ab + kk);
        *(float4*)&fa[4] = *(const float4*)(Ab + kk + 4);
        size_t boff = (size_t)((kk >> 3) + bchunk) * WCOLS * 8
                    + (size_t)(col0 + bcol) * 8;
        bhv = *(const s16x8*)(Whb + boff);
        blv = *(const s16x8*)(Wlb + boff);
    };
    auto stage = [&](int buf) {
#pragma unroll
        for (int q = 0; q < 2; q++) {
            unsigned u0 = __float_as_uint(fa[q * 4 + 0]);
            unsigned u1 = __float_as_uint(fa[q * 4 + 1]);
            unsigned u2 = __float_as_uint(fa[q * 4 + 2]);
            unsigned u3 = __float_as_uint(fa[q * 4 + 3]);
            float r0 = fa[q * 4 + 0] - __uint_as_float(u0 & 0xFFFF0000u);
            float r1 = fa[q * 4 + 1] - __uint_as_float(u1 & 0xFFFF0000u);
            float r2 = fa[q * 4 + 2] - __uint_as_float(u2 & 0xFFFF0000u);
            float r3 = fa[q * 4 + 3] - __uint_as_float(u3 & 0xFFFF0000u);
            uint2 th, tl;
            th.x = packhi(u1, u0); th.y = packhi(u3, u2);
            tl.x = packhi(__float_as_uint(r1), __float_as_uint(r0));
            tl.y = packhi(__float_as_uint(r3), __float_as_uint(r2));
            int kq = aoff + q * 4;
            int base = ((kq >> 3) * 64 + arow) * 8 + (kq & 7);
            *(uint2*)&Ah[buf][base] = th;
            *(uint2*)&Al[buf][base] = tl;
        }
        *(s16x8*)&Bh[buf][bsel] = bhv;
        *(s16x8*)&Bl[buf][bsel] = blv;
    };

    loadrg(0);
    stage(0);
    if (Kp > 32) loadrg(32);
    barrier_lds();

    for (int k0 = 0; k0 < Kp; k0 += 32) {
        const int cur = (k0 >> 5) & 1;
        s16x8 Afh[2], Afl[2], Bfh[2], Bfl[2];
#pragma unroll
        for (int fr = 0; fr < 2; fr++) {
            int off = (kch * 64 + wm * 32 + fr * 16 + m) * 8;
            Afh[fr] = *(const s16x8*)&Ah[cur][off];
            Afl[fr] = *(const s16x8*)&Al[cur][off];
        }
#pragma unroll
        for (int fc = 0; fc < 2; fc++) {
            int off = ((kch << 6) + wn * 32 + fc * 16 + m) * 8;
            Bfh[fc] = *(const s16x8*)&Bh[cur][off];
            Bfl[fc] = *(const s16x8*)&Bl[cur][off];
        }
        if (k0 + 32 < Kp) {
            stage(cur ^ 1);             // consumes regs loaded last iteration
            if (k0 + 64 < Kp) loadrg(k0 + 64);   // issue 1 iteration ahead
        }
#pragma unroll
        for (int fr = 0; fr < 2; fr++)
#pragma unroll
            for (int fc = 0; fc < 2; fc++) {
                mfma16(acc[fr][fc], Afh[fr], Bfh[fc]);
                mfma16(acc[fr][fc], Afl[fr], Bfh[fc]);
                mfma16(acc[fr][fc], Afh[fr], Bfl[fc]);
            }
        barrier_lds();
    }
}

// ---------------------------------------------------------------------------
// xf: [ h-split | si | sjT ] = X @ F + bias (448 cols). 1D grid:
// blocks [0,448) GEMM; FC: blocks [448,660) run layer-1 weight conversion.
// ---------------------------------------------------------------------------
template<bool FC>
__global__ void __launch_bounds__(256) xf_kernel(
    const float* __restrict__ X, int Kp,
    const ushort* __restrict__ Fh, const ushort* __restrict__ Fl,
    const float* __restrict__ bias,
    ushort* __restrict__ Hh, ushort* __restrict__ Hl,
    float* __restrict__ si, float* __restrict__ sjT,
    const float* __restrict__ W1, const float* __restrict__ b1,
    const float* __restrict__ A1, const float* __restrict__ ab1,
    ushort* __restrict__ F1h, ushort* __restrict__ F1l,
    float* __restrict__ bias1) {
    if (FC && blockIdx.x >= 448) {
        // fused layer-1 conversion: [0,12800) W1-split, [12800,53760) WA1,
        // [53760,54208) bias1
        int idx = (blockIdx.x - 448) * 256 + threadIdx.x;
        if (idx >= 54208) return;
        if (idx < 12800) {
            do_wsplit(W1, 300, idx / 320, idx % 320, F1h, F1l);
        } else if (idx < 53760) {
            int i2 = idx - 12800;
            do_wa(W1, 300, i2 >> 7, i2 & 127, A1, F1h, F1l);
        } else {
            do_bias(b1, idx - 53760, A1, ab1, bias1);
        }
        return;
    }
    const int tid = threadIdx.x;
    const int lane = tid & 63, wave = tid >> 6;
    const int wm = wave >> 1, wn = wave & 1;
    const int m = lane & 15, kch = lane >> 4;
    const int bid = blockIdx.x;
    const int col0 = (bid % 7) * 64, row0 = (bid / 7) * 64;

    f32x4 acc[2][2];
#pragma unroll
    for (int i = 0; i < 2; i++)
#pragma unroll
        for (int j = 0; j < 2; j++)
#pragma unroll
            for (int e = 0; e < 4; e++) acc[i][j][e] = 0.f;

    const float* Ab = X + (size_t)(row0 + (tid >> 2)) * Kp + (tid & 3) * 8;
    gemm_core(Ab, Fh, Fl, 448, col0, Kp, acc);
    asm volatile("s_nop 7\ns_nop 7\ns_nop 7" ::);   // MFMA->VALU hazard guard

#pragma unroll
    for (int fr = 0; fr < 2; fr++) {
        int rbase = row0 + wm * 32 + fr * 16 + (kch << 2);
#pragma unroll
        for (int fc = 0; fc < 2; fc++) {
            int col = col0 + wn * 32 + fc * 16 + m;
            float bv = bias[col];
            float vv[4];
#pragma unroll
            for (int e = 0; e < 4; e++) vv[e] = acc[fr][fc][e] + bv;
            if (col < 320) {           // h -> hi/lo split, H slab layout
                unsigned u0 = __float_as_uint(vv[0]);
                unsigned u1 = __float_as_uint(vv[1]);
                unsigned u2 = __float_as_uint(vv[2]);
                unsigned u3 = __float_as_uint(vv[3]);
                float r0 = vv[0] - __uint_as_float(u0 & 0xFFFF0000u);
                float r1 = vv[1] - __uint_as_float(u1 & 0xFFFF0000u);
                float r2 = vv[2] - __uint_as_float(u2 & 0xFFFF0000u);
                float r3 = vv[3] - __uint_as_float(u3 & 0xFFFF0000u);
                uint2 th, tl;
                th.x = packhi(u1, u0); th.y = packhi(u3, u2);
                tl.x = packhi(__float_as_uint(r1), __float_as_uint(r0));
                tl.y = packhi(__float_as_uint(r3), __float_as_uint(r2));
                int k = rbase & 255, bb = rbase >> 8;
                size_t dst = (size_t)bb * 81920 + ((size_t)(k >> 3) * 320 + col) * 8 + (k & 7);
                *(uint2*)&Hh[dst] = th;
                *(uint2*)&Hl[dst] = tl;
            } else if (col < 384) {    // si fp32
                int cc = col - 320;
#pragma unroll
                for (int e = 0; e < 4; e++)
                    si[(size_t)(rbase + e) * 64 + cc] = vv[e];
            } else {                   // sjT fp32 (transposed, coalesced)
                int cc = col - 384;
                int bb = rbase >> 8, j0 = rbase & 255;
                float4 v4 = make_float4(vv[0], vv[1], vv[2], vv[3]);
                *(float4*)&sjT[((size_t)(bb * 64 + cc)) * Nc + j0] = v4;
            }
        }
    }
}

// ---------------------------------------------------------------------------
// scores: e = leaky(a2 . relu(si+sj)), mask, per-row max/sum-exp,
// P = exp(e - rowmax) fp32. grid (16 batches, 32 row-tiles of 8).
// ---------------------------------------------------------------------------
__global__ void __launch_bounds__(256) scores_kernel(
    const float* __restrict__ si, const float* __restrict__ sjT,
    const float* __restrict__ adj, const float* __restrict__ A2,
    const float* __restrict__ ab2p,
    float* __restrict__ P, float* __restrict__ rmx, float* __restrict__ rsm) {
    int b = blockIdx.x, ic = blockIdx.y;
    const int j = threadIdx.x;
    __shared__ __align__(16) float sis[8][68];
    __shared__ __align__(16) float a2s[64];
    __shared__ __align__(16) float E[8][260];

    if (j < 64) a2s[j] = A2[j];
#pragma unroll
    for (int idx = j, t = 0; t < 2; t++, idx += 256) {
        int r = idx >> 6, h = idx & 63;
        sis[r][h] = si[(size_t)(b * Nc + ic * 8 + r) * 64 + h];
    }
    float sv[64];
    const float* sjb = sjT + ((size_t)b << 6) * Nc + j;
#pragma unroll
    for (int h = 0; h < 64; h++) sv[h] = sjb[(size_t)h * Nc];
    __syncthreads();

    float acc[8] = {};
#pragma unroll
    for (int hq = 0; hq < 16; hq++) {
        float4 a2q = *(const float4*)&a2s[hq * 4];
#pragma unroll
        for (int r = 0; r < 8; r++) {
            const float4 siq = *(const float4*)&sis[r][hq * 4];
            acc[r] += a2q.x * fmaxf(siq.x + sv[hq * 4 + 0], 0.f)
                    + a2q.y * fmaxf(siq.y + sv[hq * 4 + 1], 0.f)
                    + a2q.z * fmaxf(siq.z + sv[hq * 4 + 2], 0.f)
                    + a2q.w * fmaxf(siq.w + sv[hq * 4 + 3], 0.f);
        }
    }
    float ab2v = ab2p[0];
    const float* adjp = adj + (size_t)(b * Nc + ic * 8) * Nc + j;
#pragma unroll
    for (int r = 0; r < 8; r++) {
        float e = acc[r] + ab2v;
        e = e > 0.f ? e : SLOPEc * e;
        float a = adjp[(size_t)r * Nc];
        E[r][j] = (a != 0.f) ? e : NEGc;
    }
    __syncthreads();
    int wv = j >> 6, lane = j & 63;
#pragma unroll
    for (int rr = 0; rr < 2; rr++) {
        int r = wv * 2 + rr;
        float4 q = *(const float4*)&E[r][lane * 4];
        float m4 = fmaxf(fmaxf(q.x, q.y), fmaxf(q.z, q.w));
        float rm = wredMax(m4);
        float4 p;
        p.x = expf(q.x - rm); p.y = expf(q.y - rm);
        p.z = expf(q.z - rm); p.w = expf(q.w - rm);
        float rs = wredSum(p.x + p.y + p.z + p.w);
        int gi = ic * 8 + r;
        *(float4*)(P + (size_t)(b * Nc + gi) * Nc + lane * 4) = p;
        if (lane == 0) { rmx[b * Nc + gi] = rm; rsm[b * Nc + gi] = rs; }
    }
}

// ---------------------------------------------------------------------------
// pv: out = softmax_scale * (P @ H), flat-softmax merge fused in prologue.
// grid (5 col-tiles, 4 row-tiles, 16 batches)
// ---------------------------------------------------------------------------
__global__ void __launch_bounds__(256) pv_kernel(
    const float* __restrict__ P,
    const ushort* __restrict__ Hh, const ushort* __restrict__ Hl,
    const float* __restrict__ rmx, const float* __restrict__ rsm,
    float* __restrict__ out, int OS) {
    __shared__ float sclS[256];
    __shared__ float mb[4], sb[4];
    const int tid = threadIdx.x;
    const int lane = tid & 63, wave = tid >> 6;
    const int col0 = blockIdx.x * 64, row0 = blockIdx.y * 64;
    const int b = blockIdx.z;

    {   // flat-softmax merge: scale_i = exp(m_i - M)/S
        float mv = rmx[b * 256 + tid];
        float wmx = wredMax(mv);
        if (!lane) mb[wave] = wmx;
        __syncthreads();
        float M = fmaxf(fmaxf(mb[0], mb[1]), fmaxf(mb[2], mb[3]));
        float ex = expf(mv - M);
        float ws = wredSum(rsm[b * 256 + tid] * ex);
        if (!lane) sb[wave] = ws;
        __syncthreads();
        float S = sb[0] + sb[1] + sb[2] + sb[3];
        sclS[tid] = ex / S;
    }

    f32x4 acc[2][2];
#pragma unroll
    for (int i = 0; i < 2; i++)
#pragma unroll
        for (int j = 0; j < 2; j++)
#pragma unroll
            for (int e = 0; e < 4; e++) acc[i][j][e] = 0.f;

    const float* Ab = P + (size_t)b * 65536 + (size_t)(row0 + (tid >> 2)) * Nc + (tid & 3) * 8;
    gemm_core(Ab, Hh + (size_t)b * 81920, Hl + (size_t)b * 81920, 320, col0, 256, acc);
    asm volatile("s_nop 7\ns_nop 7\ns_nop 7" ::);

    const int wm = wave >> 1, wn = wave & 1;
    const int m = lane & 15, kch = lane >> 4;
    float* ob = out + (size_t)b * 256 * OS;
#pragma unroll
    for (int fr = 0; fr < 2; fr++) {
        int rbase = row0 + wm * 32 + fr * 16 + (kch << 2);
#pragma unroll
        for (int fc = 0; fc < 2; fc++) {
            int col = col0 + wn * 32 + fc * 16 + m;
            if (col < OS) {
#pragma unroll
                for (int e = 0; e < 4; e++)
                    ob[(size_t)(rbase + e) * OS + col] = acc[fr][fc][e] * sclS[rbase + e];
            }
        }
    }
}

// ---------------------------------------------------------------------------
extern "C" void kernel_launch(void* const* d_in, const int* in_sizes, int n_in,
                              void* d_out, int out_size, void* d_ws, size_t ws_size,
                              hipStream_t stream) {
    const float* adj     = (const float*)d_in[0];
    const float* feature = (const float*)d_in[1];
    const float* W0      = (const float*)d_in[2];
    const float* b0      = (const float*)d_in[3];
    const float* W1      = (const float*)d_in[4];
    const float* b1      = (const float*)d_in[5];
    const float* A1      = (const float*)d_in[6];
    const float* ab1     = (const float*)d_in[7];
    const float* A2      = (const float*)d_in[8];
    const float* ab2     = (const float*)d_in[9];

    char* ws = (char*)d_ws;
    float*  x1    = (float*)(ws);                  // 4096x320      5,242,880
    float*  si    = (float*)(ws + 5242880);        //               1,048,576
    float*  sjT   = (float*)(ws + 6291456);        //               1,048,576
    float*  P     = (float*)(ws + 7340032);        // 16x256x256    4,194,304
    float*  rmx   = (float*)(ws + 11534336);       //               16,384
    float*  rsm   = (float*)(ws + 11550720);       //               16,384
    float*  bias0 = (float*)(ws + 11567104);       //               1,792
    float*  bias1 = (float*)(ws + 11568896);       //               1,792
    ushort* F0h   = (ushort*)(ws + 11570688);      //               688,128
    ushort* F0l   = (ushort*)(ws + 12258816);      //               688,128
    ushort* F1h   = (ushort*)(ws + 12946944);      //               286,720
    ushort* F1l   = (ushort*)(ws + 13233664);      //               286,720
    ushort* Hh    = (ushort*)(ws + 13520384);      // 16 x 81920    2,621,440
    ushort* Hl    = (ushort*)(ws + 16141824);      //               2,621,440
    float* outp   = (float*)d_out;

    convert0<<<506, 256, 0, stream>>>(W0, b0, A1, ab1, F0h, F0l, bias0);

    // layer 0 (+ fused layer-1 weight conversion in blocks 448..659)
    xf_kernel<true><<<660, 256, 0, stream>>>(
        feature, 768, F0h, F0l, bias0, Hh, Hl, si, sjT,
        W1, b1, A1, ab1, F1h, F1l, bias1);
    scores_kernel<<<dim3(16, 32), 256, 0, stream>>>(
        si, sjT, adj, A2, ab2, P, rmx, rsm);
    pv_kernel<<<dim3(5, 4, 16), 256, 0, stream>>>(
        P, Hh, Hl, rmx, rsm, x1, 320);

    // layer 1
    xf_kernel<false><<<448, 256, 0, stream>>>(
        x1, 320, F1h, F1l, bias1, Hh, Hl, si, sjT,
        nullptr, nullptr, nullptr, nullptr, nullptr, nullptr, nullptr);
    scores_kernel<<<dim3(16, 32), 256, 0, stream>>>(
        si, sjT, adj, A2, ab2, P, rmx, rsm);
    pv_kernel<<<dim3(5, 4, 16), 256, 0, stream>>>(
        P, Hh, Hl, rmx, rsm, outp, 300);
}